// Round 9
// baseline (187.912 us; speedup 1.0000x reference)
//
#include <hip/hip_runtime.h>
#include <stdint.h>

#define NSIG   32768
#define NATOM  512
#define MDIM   64
#define SPAR   5
#define EPS    1e-10

// ---- prep: fp64 norms; Dt32 [dim][atom] f32; Dt64 [dim][atom] f64;
// ----       Dd64 [atom][dim] f64; rnrm = 1/(||d||^2+eps) f64
__global__ __launch_bounds__(512) void prep_kernel(const float* __restrict__ D,
                                                   float*  __restrict__ Dt32,
                                                   double* __restrict__ Dt64,
                                                   double* __restrict__ Dd64,
                                                   double* __restrict__ rnrm) {
  int n = threadIdx.x;                 // atom 0..511
  double ss = 0.0;
#pragma unroll 8
  for (int c = 0; c < MDIM; ++c) {
    double v = (double)D[c * NATOM + n];
    ss += v * v;
  }
  double norm = sqrt(ss);
  if (norm < 1e-10) norm = 1e-10;
  double s2 = 0.0;
#pragma unroll 8
  for (int c = 0; c < MDIM; ++c) {
    double v = (double)D[c * NATOM + n] / norm;
    Dt64[(size_t)c * NATOM + n] = v;
    Dd64[((size_t)n << 6) + c]  = v;
    Dt32[(size_t)c * NATOM + n] = (float)v;
    s2 += v * v;
  }
  rnrm[n] = 1.0 / (s2 + EPS);
}

// ---- Gram matrix in f32 (steers the f32 corr recursion only) ---------------
__global__ __launch_bounds__(512) void gram_kernel(const float* __restrict__ Dt32,
                                                   float* __restrict__ G32) {
  int i = blockIdx.x;
  int j = threadIdx.x;
  float s = 0.f;
#pragma unroll 8
  for (int c = 0; c < MDIM; ++c)
    s += Dt32[(size_t)c * NATOM + i] * Dt32[(size_t)c * NATOM + j];
  G32[(size_t)i * NATOM + j] = s;
}

// ---- repack: xw[l][c*32+b] = z_e[b][c][l], coalesced via LDS transpose -----
// block: one dim c, one 32-l tile, all 32 b. Reads and writes 128 B runs.
__global__ __launch_bounds__(256) void repack_kernel(const float* __restrict__ z_e,
                                                     float* __restrict__ xw) {
  __shared__ float t[32][33];
  const int c  = blockIdx.x & 63;
  const int l0 = (blockIdx.x >> 6) << 5;
  const int tr = threadIdx.x >> 5;       // 0..7
  const int tc = threadIdx.x & 31;
#pragma unroll
  for (int p = 0; p < 4; ++p) {
    int b = tr + p * 8;
    t[b][tc] = z_e[(size_t)b * 65536 + (size_t)c * 1024 + l0 + tc];
  }
  __syncthreads();
#pragma unroll
  for (int p = 0; p < 4; ++p) {
    int lr = tr + p * 8;
    xw[(size_t)(l0 + lr) * 2048 + c * 32 + tc] = t[tc][lr];
  }
}

// ---- main OMP kernel: fp32 GEMM/scan/Gram + group-parallel fp64 refinement --
// block = 256 = 4 waves, 32 sigs/block (token l). Wave w owns sigs [8w,8w+8),
// covers all 512 atoms. Atom-map: lane owns atoms [lane*8,lane*8+8) (cor[8][8]).
// Group-map: lane (gsi=lane>>3, lg=lane&7) holds fp64 residual dims
// [8lg,8lg+8) of signal w*8+gsi in registers.
__global__ __launch_bounds__(256, 4) void omp9_kernel(const float* __restrict__ xw,
                                                      const float* __restrict__ Dt32,
                                                      const double* __restrict__ Dt64,
                                                      const double* __restrict__ Dd64,
                                                      const double* __restrict__ rnrm,
                                                      const float* __restrict__ G32,
                                                      float* __restrict__ z_dl,
                                                      float* __restrict__ coeff,
                                                      double* __restrict__ partial) {
  __shared__ float  xs[2048];              // 8 KiB  x f32, xw block slice
  __shared__ double s_al[SPAR][32];
  __shared__ int    s_sel[SPAR][32];
  __shared__ double s_red[4];

  const int tid  = threadIdx.x;
  const int w    = __builtin_amdgcn_readfirstlane(tid >> 6);
  const int lane = tid & 63;
  const int abase = lane << 3;             // atom-map: this lane's 8 atoms
  const int gsi  = lane >> 3;              // group-map: signal within wave
  const int lg   = lane & 7;               // group-map: dim-oct
  const int sig  = (w << 3) + gsi;         // signal within block
  const int bid  = blockIdx.x;
  const int l    = ((bid & 7) << 7) | (bid >> 3);   // XCD swizzle (bijective)

  // ---- stage x slice into LDS (coalesced) ----
  {
    const float* src = xw + (size_t)l * 2048 + tid * 8;
    float4 v0 = *(const float4*)src;
    float4 v1 = *(const float4*)(src + 4);
    *(float4*)&xs[tid * 8]     = v0;
    *(float4*)&xs[tid * 8 + 4] = v1;
  }
  __syncthreads();

  float cor[8][8];                         // [atom][sig] f32
#pragma unroll
  for (int a = 0; a < 8; ++a)
#pragma unroll
    for (int si = 0; si < 8; ++si) cor[a][si] = 0.0f;

  // ---- phase 1: f32 register GEMM, 2-deep D prefetch, x from LDS ----
  {
    const float* dbase = Dt32 + abase;
    const int xo = w << 3;
    float4 dA0 = *(const float4*)dbase;
    float4 dB0 = *(const float4*)(dbase + 4);
    float4 dA1 = *(const float4*)(dbase + NATOM);
    float4 dB1 = *(const float4*)(dbase + NATOM + 4);
    for (int k = 0; k < MDIM; k += 2) {
      float4 xA0 = *(const float4*)&xs[k * 32 + xo];
      float4 xB0 = *(const float4*)&xs[k * 32 + xo + 4];
      float4 xA1 = *(const float4*)&xs[(k + 1) * 32 + xo];
      float4 xB1 = *(const float4*)&xs[(k + 1) * 32 + xo + 4];
      float dv0[8] = {dA0.x, dA0.y, dA0.z, dA0.w, dB0.x, dB0.y, dB0.z, dB0.w};
      float xv0[8] = {xA0.x, xA0.y, xA0.z, xA0.w, xB0.x, xB0.y, xB0.z, xB0.w};
      float dv1[8] = {dA1.x, dA1.y, dA1.z, dA1.w, dB1.x, dB1.y, dB1.z, dB1.w};
      float xv1[8] = {xA1.x, xA1.y, xA1.z, xA1.w, xB1.x, xB1.y, xB1.z, xB1.w};
      if (k + 2 < MDIM) {
        const float* dn = dbase + (size_t)(k + 2) * NATOM;
        dA0 = *(const float4*)dn; dB0 = *(const float4*)(dn + 4);
        const float* dm = dbase + (size_t)(k + 3) * NATOM;
        dA1 = *(const float4*)dm; dB1 = *(const float4*)(dm + 4);
      }
#pragma unroll
      for (int a = 0; a < 8; ++a)
#pragma unroll
        for (int si = 0; si < 8; ++si)
          cor[a][si] += dv0[a] * xv0[si];
#pragma unroll
      for (int a = 0; a < 8; ++a)
#pragma unroll
        for (int si = 0; si < 8; ++si)
          cor[a][si] += dv1[a] * xv1[si];
    }
  }

  // ---- fp64 residual in registers (group-mapped) ----
  double rr[8];
#pragma unroll
  for (int j = 0; j < 8; ++j)
    rr[j] = (double)xs[(lg * 8 + j) * 32 + sig];

  unsigned long long mk = ~0ull;           // atom-map availability bit (a*8+si)

#pragma unroll 1
  for (int it = 0; it < SPAR; ++it) {
    // ---- f32 keyscan (atom-mapped), identical semantics to R8 ----
    unsigned int kb[8];
#pragma unroll
    for (int si = 0; si < 8; ++si) {
      unsigned int best = 0;
#pragma unroll
      for (int a = 0; a < 8; ++a) {
        float ac = fabsf(cor[a][si]);
        unsigned int enc = (unsigned int)(511 - (abase + a));
        unsigned int kv = (__float_as_uint(ac) & 0xFFFFFC00u) | enc;
        bool avail = (mk >> ((a << 3) + si)) & 1ull;
        kv = avail ? kv : enc;             // masked competes as value 0 (np mask)
        best = best > kv ? best : kv;
      }
      kb[si] = best;
    }
#pragma unroll
    for (int o = 1; o < 8; o <<= 1)
#pragma unroll
      for (int si = 0; si < 8; ++si) {
        unsigned int ok = __shfl_xor(kb[si], o);
        kb[si] = kb[si] > ok ? kb[si] : ok;
      }
    unsigned int kk = kb[0];
#pragma unroll
    for (int si = 1; si < 8; ++si) kk = ((lane & 7) == si) ? kb[si] : kk;
#pragma unroll
    for (int o = 8; o < 64; o <<= 1) {
      unsigned int ok = __shfl_xor(kk, o);
      kk = kk > ok ? kk : ok;
    }
    // lane s in 0..7 now holds winner key of si=s (any lane with lane&7==s does)

    // ---- group-parallel fp64 winner dot (all 8 si at once) ----
    const unsigned int wkg = __shfl(kk, gsi);     // my group's winner key
    const int gig = 511 - (int)(wkg & 0x1FFu);
    double dw[8];
    {
      const double2* dp = (const double2*)(Dd64 + ((size_t)gig << 6) + (lg << 3));
      double2 q0 = dp[0], q1 = dp[1], q2 = dp[2], q3 = dp[3];
      dw[0]=q0.x; dw[1]=q0.y; dw[2]=q1.x; dw[3]=q1.y;
      dw[4]=q2.x; dw[5]=q2.y; dw[6]=q3.x; dw[7]=q3.y;
    }
    double p = ((dw[0]*rr[0] + dw[1]*rr[1]) + (dw[2]*rr[2] + dw[3]*rr[3]))
             + ((dw[4]*rr[4] + dw[5]*rr[5]) + (dw[6]*rr[6] + dw[7]*rr[7]));
    p += __shfl_xor(p, 1); p += __shfl_xor(p, 2); p += __shfl_xor(p, 4);
    unsigned long long bkey =
      ((unsigned long long)__double_as_longlong(fabs(p)) & ~0x3FFull)
      | (unsigned long long)(511 - gig);
    double bcor = p;
    int bgi = gig;

    // ---- pending extras mask (atom-mapped, bit (a<<3)+si) ----
    unsigned long long pend = 0ull;
#pragma unroll
    for (int si = 0; si < 8; ++si) {
      unsigned int wks = __shfl(kk, si);
      int widx = 511 - (int)(wks & 0x1FFu);
      float thr = __uint_as_float(wks & 0xFFFFFC00u) * 0.999f;
#pragma unroll
      for (int a = 0; a < 8; ++a) {
        bool avail = (mk >> ((a << 3) + si)) & 1ull;
        bool inb = avail && (thr > 0.0f) && (fabsf(cor[a][si]) >= thr)
                 && ((abase + a) != widx);
        pend |= inb ? (1ull << ((a << 3) + si)) : 0ull;
      }
    }
    // ---- rare: refine extra candidates, one per si per pass ----
    while (__any(pend != 0ull)) {
      int myext = -1;
#pragma unroll
      for (int si = 0; si < 8; ++si) {
        unsigned long long m8 = (pend >> si) & 0x0101010101010101ull;
        unsigned long long bal = __ballot(m8 != 0ull);
        int ge = -1;
        if (bal != 0ull) {
          int src = __ffsll((long long)bal) - 1;
          unsigned long long pm = __shfl(m8, src);
          int a0 = (__ffsll((long long)pm) - 1) >> 3;
          ge = (src << 3) + a0;
        }
        if (lane == si) myext = ge;
        if (ge >= 0 && (ge >> 3) == lane)
          pend &= ~(1ull << (((ge & 7) << 3) + si));
      }
      int gie = __shfl(myext, gsi);        // group-uniform
      if (gie >= 0) {
        double de[8];
        const double2* dp = (const double2*)(Dd64 + ((size_t)gie << 6) + (lg << 3));
        double2 q0 = dp[0], q1 = dp[1], q2 = dp[2], q3 = dp[3];
        de[0]=q0.x; de[1]=q0.y; de[2]=q1.x; de[3]=q1.y;
        de[4]=q2.x; de[5]=q2.y; de[6]=q3.x; de[7]=q3.y;
        double pe = ((de[0]*rr[0] + de[1]*rr[1]) + (de[2]*rr[2] + de[3]*rr[3]))
                  + ((de[4]*rr[4] + de[5]*rr[5]) + (de[6]*rr[6] + de[7]*rr[7]));
        pe += __shfl_xor(pe, 1); pe += __shfl_xor(pe, 2); pe += __shfl_xor(pe, 4);
        unsigned long long ke =
          ((unsigned long long)__double_as_longlong(fabs(pe)) & ~0x3FFull)
          | (unsigned long long)(511 - gie);
        if (ke > bkey) { bkey = ke; bcor = pe; bgi = gie; }
      }
    }

    // ---- finalize winner per group ----
    double alpha = bcor * rnrm[bgi];
    if (lg == 0) { s_sel[it][sig] = bgi; s_al[it][sig] = alpha; }
    // mk clear (atom-mapped owner lane), per si
#pragma unroll
    for (int si = 0; si < 8; ++si) {
      int gf = __shfl(bgi, si << 3);
      if ((gf >> 3) == lane) mk &= ~(1ull << (((gf & 7) << 3) + si));
    }

    if (it != SPAR - 1) {
      // fp64 residual update (group-mapped); reuse dw when winner unchanged
      if (bgi == gig) {
#pragma unroll
        for (int j = 0; j < 8; ++j) rr[j] -= alpha * dw[j];
      } else {
        const double2* dp = (const double2*)(Dd64 + ((size_t)bgi << 6) + (lg << 3));
        double2 q0 = dp[0], q1 = dp[1], q2 = dp[2], q3 = dp[3];
        rr[0] -= alpha*q0.x; rr[1] -= alpha*q0.y; rr[2] -= alpha*q1.x; rr[3] -= alpha*q1.y;
        rr[4] -= alpha*q2.x; rr[5] -= alpha*q2.y; rr[6] -= alpha*q3.x; rr[7] -= alpha*q3.y;
      }
      // f32 Gram recursion (atom-mapped), all 8 G-rows batched
      float afs[8]; int gfs[8];
#pragma unroll
      for (int si = 0; si < 8; ++si) {
        gfs[si] = __shfl(bgi, si << 3);
        afs[si] = (float)__shfl(alpha, si << 3);
      }
#pragma unroll
      for (int si = 0; si < 8; ++si) {
        const float* gp = G32 + (size_t)gfs[si] * NATOM + abase;
        float4 g0 = *(const float4*)gp;
        float4 g1 = *(const float4*)(gp + 4);
        cor[0][si] -= afs[si]*g0.x; cor[1][si] -= afs[si]*g0.y;
        cor[2][si] -= afs[si]*g0.z; cor[3][si] -= afs[si]*g0.w;
        cor[4][si] -= afs[si]*g1.x; cor[5][si] -= afs[si]*g1.y;
        cor[6][si] -= afs[si]*g1.z; cor[7][si] -= afs[si]*g1.w;
      }
    }
  }
  __syncthreads();                         // publish s_sel/s_al to all waves

  // ---- epilogue A: z_dl (fp64) + loss ----
  const int s = tid & 31;
  {
    const int c0 = tid >> 5;               // 0..7
    double s2 = 0.0;
#pragma unroll
    for (int r = 0; r < 8; ++r) {
      int c = c0 + (r << 3);
      double v = s_al[0][s] * Dt64[(size_t)c * NATOM + s_sel[0][s]];
#pragma unroll
      for (int tt = 1; tt < SPAR; ++tt)
        v += s_al[tt][s] * Dt64[(size_t)c * NATOM + s_sel[tt][s]];
      float zv = (float)v;
      z_dl[((size_t)s * MDIM + c) * 1024 + l] = zv;
      double x = (double)xs[(c << 5) + s];
      double diff = (double)zv - x;
      s2 += diff * diff;
    }
#pragma unroll
    for (int o = 32; o > 0; o >>= 1) s2 += __shfl_down(s2, o);
    if (lane == 0) s_red[w] = s2;
  }
  __syncthreads();
  if (tid == 0) partial[bid] = (s_red[0] + s_red[1]) + (s_red[2] + s_red[3]);

  // ---- epilogue B: coeff = zero-fill + sparse scatter ----
  {
    const float4 z4 = make_float4(0.f, 0.f, 0.f, 0.f);
#pragma unroll
    for (int p = 0; p < 16; ++p) {
      int idx = tid + (p << 8);            // 0..4095 = atom*8 + quad
      int a = idx >> 3, q = idx & 7;
      *(float4*)(coeff + (size_t)a * NSIG + ((size_t)l << 5) + (q << 2)) = z4;
    }
  }
  __syncthreads();                         // order zeros before scatter (same L2)
  if (tid < 32) {
#pragma unroll
    for (int tt = 0; tt < SPAR; ++tt) {
      int gi = s_sel[tt][tid];
      coeff[(size_t)gi * NSIG + ((size_t)l << 5) + tid] = (float)s_al[tt][tid];
    }
  }
}

// ---- finalize loss ---------------------------------------------------------
__global__ __launch_bounds__(64) void finalize_kernel(const double* __restrict__ partial,
                                                      float* __restrict__ loss_out) {
  double s = 0.0;
  for (int i = threadIdx.x; i < 1024; i += 64) s += partial[i];
#pragma unroll
  for (int o = 32; o > 0; o >>= 1) s += __shfl_down(s, o);
  if (threadIdx.x == 0) loss_out[0] = (float)(1.25 * s / 2097152.0);
}

extern "C" void kernel_launch(void* const* d_in, const int* in_sizes, int n_in,
                              void* d_out, int out_size, void* d_ws, size_t ws_size,
                              hipStream_t stream) {
  const float* z_e = (const float*)d_in[0];
  const float* D   = (const float*)d_in[1];

  float* out      = (float*)d_out;
  float* z_dl     = out;                       // 2097152 elems
  float* loss_out = out + 2097152;             // 1 elem
  float* coeff    = out + 2097153;             // 512*32768 elems

  char*   ws      = (char*)d_ws;
  double* partial = (double*)ws;                               // 8 KiB (1024)
  float*  Dt32    = (float*) (ws + 8192);                      // 128 KiB
  double* Dt64    = (double*)(ws + 8192 + 131072);             // 256 KiB
  double* Dd64    = (double*)(ws + 8192 + 131072 + 262144);    // 256 KiB
  double* rnrm    = (double*)(ws + 8192 + 131072 + 524288);    // 4 KiB
  float*  G32     = (float*) (ws + 8192 + 131072 + 524288 + 4096);           // 1 MiB
  float*  xw      = (float*) (ws + 8192 + 131072 + 524288 + 4096 + 1048576); // 8 MiB

  prep_kernel<<<1, 512, 0, stream>>>(D, Dt32, Dt64, Dd64, rnrm);
  gram_kernel<<<NATOM, NATOM, 0, stream>>>(Dt32, G32);
  repack_kernel<<<2048, 256, 0, stream>>>(z_e, xw);
  omp9_kernel<<<1024, 256, 0, stream>>>(xw, Dt32, Dt64, Dd64, rnrm, G32,
                                        z_dl, coeff, partial);
  finalize_kernel<<<1, 64, 0, stream>>>(partial, loss_out);
}

// Round 10
// 152.201 us; speedup vs baseline: 1.2346x; 1.2346x over previous
//
#include <hip/hip_runtime.h>
#include <stdint.h>

#define NSIG   32768
#define NATOM  512
#define MDIM   64
#define SPAR   5
#define EPS    1e-10

// ---- prep: fp64 norms; Dt32 [dim][atom] f32; Dt64 [dim][atom] f64;
// ----       Dd64 [atom][dim] f64; rnrm = 1/(||d||^2+eps) f64
__global__ __launch_bounds__(512) void prep_kernel(const float* __restrict__ D,
                                                   float*  __restrict__ Dt32,
                                                   double* __restrict__ Dt64,
                                                   double* __restrict__ Dd64,
                                                   double* __restrict__ rnrm) {
  int n = threadIdx.x;                 // atom 0..511
  double ss = 0.0;
#pragma unroll 8
  for (int c = 0; c < MDIM; ++c) {
    double v = (double)D[c * NATOM + n];
    ss += v * v;
  }
  double norm = sqrt(ss);
  if (norm < 1e-10) norm = 1e-10;
  double s2 = 0.0;
#pragma unroll 8
  for (int c = 0; c < MDIM; ++c) {
    double v = (double)D[c * NATOM + n] / norm;
    Dt64[(size_t)c * NATOM + n] = v;
    Dd64[((size_t)n << 6) + c]  = v;
    Dt32[(size_t)c * NATOM + n] = (float)v;
    s2 += v * v;
  }
  rnrm[n] = 1.0 / (s2 + EPS);
}

// ---- Gram matrix in f32 (steers the f32 corr recursion only) ---------------
__global__ __launch_bounds__(512) void gram_kernel(const float* __restrict__ Dt32,
                                                   float* __restrict__ G32) {
  int i = blockIdx.x;
  int j = threadIdx.x;
  float s = 0.f;
#pragma unroll 8
  for (int c = 0; c < MDIM; ++c)
    s += Dt32[(size_t)c * NATOM + i] * Dt32[(size_t)c * NATOM + j];
  G32[(size_t)i * NATOM + j] = s;
}

// ---- repack: xw[l][c*32+b] = z_e[b][c][l], coalesced via LDS transpose -----
__global__ __launch_bounds__(256) void repack_kernel(const float* __restrict__ z_e,
                                                     float* __restrict__ xw) {
  __shared__ float t[32][33];
  const int c  = blockIdx.x & 63;
  const int l0 = (blockIdx.x >> 6) << 5;
  const int tr = threadIdx.x >> 5;       // 0..7
  const int tc = threadIdx.x & 31;
#pragma unroll
  for (int p = 0; p < 4; ++p) {
    int b = tr + p * 8;
    t[b][tc] = z_e[(size_t)b * 65536 + (size_t)c * 1024 + l0 + tc];
  }
  __syncthreads();
#pragma unroll
  for (int p = 0; p < 4; ++p) {
    int lr = tr + p * 8;
    xw[(size_t)(l0 + lr) * 2048 + c * 32 + tc] = t[tc][lr];
  }
}

// ---- main OMP kernel: fp32 GEMM/scan/Gram + group-parallel fp64 refinement --
// block = 256 = 4 waves, 32 sigs/block (token l). Wave w owns sigs [8w,8w+8).
// Atom-map: lane owns atoms [lane*8,lane*8+8) (cor[8][8] f32).
// Group-map: lane (gsi=lane>>3, lg=lane&7) holds fp64 residual dims
// [8lg,8lg+8) of signal w*8+gsi in registers (rr[8]).
__global__ __launch_bounds__(256, 2) void omp10_kernel(const float* __restrict__ xw,
                                                       const float* __restrict__ Dt32,
                                                       const double* __restrict__ Dt64,
                                                       const double* __restrict__ Dd64,
                                                       const double* __restrict__ rnrm,
                                                       const float* __restrict__ G32,
                                                       float* __restrict__ z_dl,
                                                       float* __restrict__ coeff,
                                                       double* __restrict__ partial) {
  __shared__ float  xs[2048];              // 8 KiB x f32 slice
  __shared__ double s_al[SPAR][32];
  __shared__ int    s_sel[SPAR][32];
  __shared__ double s_red[4];

  const int tid  = threadIdx.x;
  const int w    = __builtin_amdgcn_readfirstlane(tid >> 6);
  const int lane = tid & 63;
  const int abase = lane << 3;             // atom-map
  const int gsi  = lane >> 3;              // group-map: signal within wave
  const int lg   = lane & 7;               // group-map: dim-oct
  const int sig  = (w << 3) + gsi;
  const int bid  = blockIdx.x;
  const int l    = ((bid & 7) << 7) | (bid >> 3);   // XCD swizzle (bijective)

  // ---- stage x slice into LDS (coalesced) ----
  {
    const float* src = xw + (size_t)l * 2048 + tid * 8;
    float4 v0 = *(const float4*)src;
    float4 v1 = *(const float4*)(src + 4);
    *(float4*)&xs[tid * 8]     = v0;
    *(float4*)&xs[tid * 8 + 4] = v1;
  }
  __syncthreads();

  float cor[8][8];                         // [atom][sig] f32
#pragma unroll
  for (int a = 0; a < 8; ++a)
#pragma unroll
    for (int si = 0; si < 8; ++si) cor[a][si] = 0.0f;

  // ---- phase 1: f32 register GEMM, 2-deep D prefetch, x broadcast from LDS --
  {
    const float* dbase = Dt32 + abase;
    const int xo = w << 3;
    float4 dA0 = *(const float4*)dbase;
    float4 dB0 = *(const float4*)(dbase + 4);
    float4 dA1 = *(const float4*)(dbase + NATOM);
    float4 dB1 = *(const float4*)(dbase + NATOM + 4);
    for (int k = 0; k < MDIM; k += 2) {
      float4 xA0 = *(const float4*)&xs[k * 32 + xo];
      float4 xB0 = *(const float4*)&xs[k * 32 + xo + 4];
      float4 xA1 = *(const float4*)&xs[(k + 1) * 32 + xo];
      float4 xB1 = *(const float4*)&xs[(k + 1) * 32 + xo + 4];
      float dv0[8] = {dA0.x, dA0.y, dA0.z, dA0.w, dB0.x, dB0.y, dB0.z, dB0.w};
      float xv0[8] = {xA0.x, xA0.y, xA0.z, xA0.w, xB0.x, xB0.y, xB0.z, xB0.w};
      float dv1[8] = {dA1.x, dA1.y, dA1.z, dA1.w, dB1.x, dB1.y, dB1.z, dB1.w};
      float xv1[8] = {xA1.x, xA1.y, xA1.z, xA1.w, xB1.x, xB1.y, xB1.z, xB1.w};
      if (k + 2 < MDIM) {
        const float* dn = dbase + (size_t)(k + 2) * NATOM;
        dA0 = *(const float4*)dn; dB0 = *(const float4*)(dn + 4);
        const float* dm = dbase + (size_t)(k + 3) * NATOM;
        dA1 = *(const float4*)dm; dB1 = *(const float4*)(dm + 4);
      }
#pragma unroll
      for (int a = 0; a < 8; ++a)
#pragma unroll
        for (int si = 0; si < 8; ++si)
          cor[a][si] += dv0[a] * xv0[si];
#pragma unroll
      for (int a = 0; a < 8; ++a)
#pragma unroll
        for (int si = 0; si < 8; ++si)
          cor[a][si] += dv1[a] * xv1[si];
    }
  }

  // ---- fp64 residual in registers (group-mapped) ----
  double rr[8];
#pragma unroll
  for (int j = 0; j < 8; ++j)
    rr[j] = (double)xs[(lg * 8 + j) * 32 + sig];

  unsigned long long mk = ~0ull;           // atom-map availability bit (a*8+si)

#pragma unroll 1
  for (int it = 0; it < SPAR; ++it) {
    // ---- f32 keyscan (atom-mapped) ----
    unsigned int kb[8];
#pragma unroll
    for (int si = 0; si < 8; ++si) {
      unsigned int best = 0;
#pragma unroll
      for (int a = 0; a < 8; ++a) {
        float ac = fabsf(cor[a][si]);
        unsigned int enc = (unsigned int)(511 - (abase + a));
        unsigned int kv = (__float_as_uint(ac) & 0xFFFFFC00u) | enc;
        bool avail = (mk >> ((a << 3) + si)) & 1ull;
        kv = avail ? kv : enc;             // masked competes as value 0
        best = best > kv ? best : kv;
      }
      kb[si] = best;
    }
#pragma unroll
    for (int o = 1; o < 8; o <<= 1)
#pragma unroll
      for (int si = 0; si < 8; ++si) {
        unsigned int ok = __shfl_xor(kb[si], o);
        kb[si] = kb[si] > ok ? kb[si] : ok;
      }
    unsigned int kk = kb[0];
#pragma unroll
    for (int si = 1; si < 8; ++si) kk = ((lane & 7) == si) ? kb[si] : kk;
#pragma unroll
    for (int o = 8; o < 64; o <<= 1) {
      unsigned int ok = __shfl_xor(kk, o);
      kk = kk > ok ? kk : ok;
    }

    // ---- group-parallel fp64 winner dot (all 8 si at once, rows not cached) --
    const unsigned int wkg = __shfl(kk, gsi);
    const int gig = 511 - (int)(wkg & 0x1FFu);
    double p;
    {
      const double2* dp = (const double2*)(Dd64 + ((size_t)gig << 6) + (lg << 3));
      double2 q0 = dp[0], q1 = dp[1], q2 = dp[2], q3 = dp[3];
      p = ((q0.x*rr[0] + q0.y*rr[1]) + (q1.x*rr[2] + q1.y*rr[3]))
        + ((q2.x*rr[4] + q2.y*rr[5]) + (q3.x*rr[6] + q3.y*rr[7]));
    }
    p += __shfl_xor(p, 1); p += __shfl_xor(p, 2); p += __shfl_xor(p, 4);
    unsigned long long bkey =
      ((unsigned long long)__double_as_longlong(fabs(p)) & ~0x3FFull)
      | (unsigned long long)(511 - gig);
    double bcor = p;
    int bgi = gig;

    // ---- pending extras mask (atom-mapped) ----
    unsigned long long pend = 0ull;
#pragma unroll
    for (int si = 0; si < 8; ++si) {
      unsigned int wks = __shfl(kk, si);
      int widx = 511 - (int)(wks & 0x1FFu);
      float thr = __uint_as_float(wks & 0xFFFFFC00u) * 0.999f;
#pragma unroll
      for (int a = 0; a < 8; ++a) {
        bool avail = (mk >> ((a << 3) + si)) & 1ull;
        bool inb = avail && (thr > 0.0f) && (fabsf(cor[a][si]) >= thr)
                 && ((abase + a) != widx);
        pend |= inb ? (1ull << ((a << 3) + si)) : 0ull;
      }
    }
    // ---- rare: refine extras, one per si per pass (group-parallel dots) ----
    while (__any(pend != 0ull)) {
      int myext = -1;
#pragma unroll
      for (int si = 0; si < 8; ++si) {
        unsigned long long m8 = (pend >> si) & 0x0101010101010101ull;
        unsigned long long bal = __ballot(m8 != 0ull);
        int ge = -1;
        if (bal != 0ull) {
          int src = __ffsll((long long)bal) - 1;
          unsigned long long pm = __shfl(m8, src);
          int a0 = (__ffsll((long long)pm) - 1) >> 3;
          ge = (src << 3) + a0;
        }
        if (lane == si) myext = ge;
        if (ge >= 0 && (ge >> 3) == lane)
          pend &= ~(1ull << (((ge & 7) << 3) + si));
      }
      int gie = __shfl(myext, gsi);        // group-uniform
      if (gie >= 0) {
        const double2* dp = (const double2*)(Dd64 + ((size_t)gie << 6) + (lg << 3));
        double2 q0 = dp[0], q1 = dp[1], q2 = dp[2], q3 = dp[3];
        double pe = ((q0.x*rr[0] + q0.y*rr[1]) + (q1.x*rr[2] + q1.y*rr[3]))
                  + ((q2.x*rr[4] + q2.y*rr[5]) + (q3.x*rr[6] + q3.y*rr[7]));
        pe += __shfl_xor(pe, 1); pe += __shfl_xor(pe, 2); pe += __shfl_xor(pe, 4);
        unsigned long long ke =
          ((unsigned long long)__double_as_longlong(fabs(pe)) & ~0x3FFull)
          | (unsigned long long)(511 - gie);
        if (ke > bkey) { bkey = ke; bcor = pe; bgi = gie; }
      }
    }

    // ---- finalize winner per group ----
    double alpha = bcor * rnrm[bgi];
    if (lg == 0) { s_sel[it][sig] = bgi; s_al[it][sig] = alpha; }
#pragma unroll
    for (int si = 0; si < 8; ++si) {
      int gf = __shfl(bgi, si << 3);
      if ((gf >> 3) == lane) mk &= ~(1ull << (((gf & 7) << 3) + si));
    }

    if (it != SPAR - 1) {
      // fp64 residual update (group-mapped; winner row reloaded, L2-hot)
      {
        const double2* dp = (const double2*)(Dd64 + ((size_t)bgi << 6) + (lg << 3));
        double2 q0 = dp[0], q1 = dp[1], q2 = dp[2], q3 = dp[3];
        rr[0] -= alpha*q0.x; rr[1] -= alpha*q0.y;
        rr[2] -= alpha*q1.x; rr[3] -= alpha*q1.y;
        rr[4] -= alpha*q2.x; rr[5] -= alpha*q2.y;
        rr[6] -= alpha*q3.x; rr[7] -= alpha*q3.y;
      }
      // f32 Gram recursion (atom-mapped), 2 rows per batch (register-lean)
#pragma unroll
      for (int sb = 0; sb < 8; sb += 2) {
        int   g0i = __shfl(bgi, sb << 3);
        float a0f = (float)__shfl(alpha, sb << 3);
        int   g1i = __shfl(bgi, (sb + 1) << 3);
        float a1f = (float)__shfl(alpha, (sb + 1) << 3);
        const float* gp0 = G32 + (size_t)g0i * NATOM + abase;
        const float* gp1 = G32 + (size_t)g1i * NATOM + abase;
        float4 u0 = *(const float4*)gp0;
        float4 u1 = *(const float4*)(gp0 + 4);
        float4 v0 = *(const float4*)gp1;
        float4 v1 = *(const float4*)(gp1 + 4);
        cor[0][sb] -= a0f*u0.x; cor[1][sb] -= a0f*u0.y;
        cor[2][sb] -= a0f*u0.z; cor[3][sb] -= a0f*u0.w;
        cor[4][sb] -= a0f*u1.x; cor[5][sb] -= a0f*u1.y;
        cor[6][sb] -= a0f*u1.z; cor[7][sb] -= a0f*u1.w;
        cor[0][sb+1] -= a1f*v0.x; cor[1][sb+1] -= a1f*v0.y;
        cor[2][sb+1] -= a1f*v0.z; cor[3][sb+1] -= a1f*v0.w;
        cor[4][sb+1] -= a1f*v1.x; cor[5][sb+1] -= a1f*v1.y;
        cor[6][sb+1] -= a1f*v1.z; cor[7][sb+1] -= a1f*v1.w;
      }
    }
  }
  __syncthreads();                         // publish s_sel/s_al to all waves

  // ---- epilogue A: z_dl (fp64) + loss ----
  const int s = tid & 31;
  {
    const int c0 = tid >> 5;               // 0..7
    double s2 = 0.0;
#pragma unroll
    for (int r = 0; r < 8; ++r) {
      int c = c0 + (r << 3);
      double v = s_al[0][s] * Dt64[(size_t)c * NATOM + s_sel[0][s]];
#pragma unroll
      for (int tt = 1; tt < SPAR; ++tt)
        v += s_al[tt][s] * Dt64[(size_t)c * NATOM + s_sel[tt][s]];
      float zv = (float)v;
      z_dl[((size_t)s * MDIM + c) * 1024 + l] = zv;
      double x = (double)xs[(c << 5) + s];
      double diff = (double)zv - x;
      s2 += diff * diff;
    }
#pragma unroll
    for (int o = 32; o > 0; o >>= 1) s2 += __shfl_down(s2, o);
    if (lane == 0) s_red[w] = s2;
  }
  __syncthreads();
  if (tid == 0) partial[bid] = (s_red[0] + s_red[1]) + (s_red[2] + s_red[3]);

  // ---- epilogue B: coeff = zero-fill + sparse scatter ----
  {
    const float4 z4 = make_float4(0.f, 0.f, 0.f, 0.f);
#pragma unroll
    for (int p2 = 0; p2 < 16; ++p2) {
      int idx = tid + (p2 << 8);           // 0..4095 = atom*8 + quad
      int a = idx >> 3, q = idx & 7;
      *(float4*)(coeff + (size_t)a * NSIG + ((size_t)l << 5) + (q << 2)) = z4;
    }
  }
  __syncthreads();                         // order zeros before scatter
  if (tid < 32) {
#pragma unroll
    for (int tt = 0; tt < SPAR; ++tt) {
      int gi = s_sel[tt][tid];
      coeff[(size_t)gi * NSIG + ((size_t)l << 5) + tid] = (float)s_al[tt][tid];
    }
  }
}

// ---- finalize loss ---------------------------------------------------------
__global__ __launch_bounds__(64) void finalize_kernel(const double* __restrict__ partial,
                                                      float* __restrict__ loss_out) {
  double s = 0.0;
  for (int i = threadIdx.x; i < 1024; i += 64) s += partial[i];
#pragma unroll
  for (int o = 32; o > 0; o >>= 1) s += __shfl_down(s, o);
  if (threadIdx.x == 0) loss_out[0] = (float)(1.25 * s / 2097152.0);
}

extern "C" void kernel_launch(void* const* d_in, const int* in_sizes, int n_in,
                              void* d_out, int out_size, void* d_ws, size_t ws_size,
                              hipStream_t stream) {
  const float* z_e = (const float*)d_in[0];
  const float* D   = (const float*)d_in[1];

  float* out      = (float*)d_out;
  float* z_dl     = out;                       // 2097152 elems
  float* loss_out = out + 2097152;             // 1 elem
  float* coeff    = out + 2097153;             // 512*32768 elems

  char*   ws      = (char*)d_ws;
  double* partial = (double*)ws;                               // 8 KiB (1024)
  float*  Dt32    = (float*) (ws + 8192);                      // 128 KiB
  double* Dt64    = (double*)(ws + 8192 + 131072);             // 256 KiB
  double* Dd64    = (double*)(ws + 8192 + 131072 + 262144);    // 256 KiB
  double* rnrm    = (double*)(ws + 8192 + 131072 + 524288);    // 4 KiB
  float*  G32     = (float*) (ws + 8192 + 131072 + 524288 + 4096);           // 1 MiB
  float*  xw      = (float*) (ws + 8192 + 131072 + 524288 + 4096 + 1048576); // 8 MiB

  prep_kernel<<<1, 512, 0, stream>>>(D, Dt32, Dt64, Dd64, rnrm);
  gram_kernel<<<NATOM, NATOM, 0, stream>>>(Dt32, G32);
  repack_kernel<<<2048, 256, 0, stream>>>(z_e, xw);
  omp10_kernel<<<1024, 256, 0, stream>>>(xw, Dt32, Dt64, Dd64, rnrm, G32,
                                         z_dl, coeff, partial);
  finalize_kernel<<<1, 64, 0, stream>>>(partial, loss_out);
}